// Round 1
// baseline (721.168 us; speedup 1.0000x reference)
//
#include <hip/hip_runtime.h>
#include <math.h>

namespace {

// detect whether `edge` is stored as int64 (high words of first 64 values all zero)
__global__ void kdet(const int* __restrict__ edge, int* __restrict__ flag) {
    int lane = threadIdx.x;
    int hw = edge[2 * lane + 1];
    unsigned long long b = __ballot(hw == 0);
    if (lane == 0) *flag = (b == ~0ull) ? 1 : 0;
}

// w3[k] = sum_j a_2[j] * a[j*384 + 256 + k]
__global__ void k0_w3(const float* __restrict__ a, const float* __restrict__ a2,
                      float* __restrict__ w3) {
    int k = threadIdx.x;
    float s = 0.f;
    for (int j = 0; j < 128; ++j) s += a2[j] * a[j * 384 + 256 + k];
    w3[k] = s;
}

// U = input @ a1^T, V = input @ a2c^T   (a12 staged transposed in 128KB LDS)
__global__ __launch_bounds__(256) void k1_uv(const float* __restrict__ input,
                                             const float* __restrict__ a,
                                             float* __restrict__ U, float* __restrict__ V,
                                             int n) {
    __shared__ float a12t[128 * 256];  // [k][c]; c<128: a1 col, c>=128: a2c col
    __shared__ float rows[8 * 128];
    for (int idx = threadIdx.x; idx < 128 * 256; idx += 256) {
        int k = idx >> 8, c = idx & 255;
        a12t[idx] = (c < 128) ? a[c * 384 + k] : a[(c - 128) * 384 + 128 + k];
    }
    __syncthreads();
    int c  = threadIdx.x & 127;
    int rg = threadIdx.x >> 7;
    for (int oct = blockIdx.x; oct * 8 < n; oct += gridDim.x) {
        int r0 = oct * 8;
        int nr = min(8, n - r0);
        for (int idx = threadIdx.x; idx < nr * 128; idx += 256)
            rows[idx] = input[(size_t)r0 * 128 + idx];
        __syncthreads();
        float accU[4] = {0.f, 0.f, 0.f, 0.f};
        float accV[4] = {0.f, 0.f, 0.f, 0.f};
        #pragma unroll 4
        for (int k = 0; k < 128; k += 2) {
            float a00 = a12t[k * 256 + c];
            float a01 = a12t[(k + 1) * 256 + c];
            float a10 = a12t[k * 256 + c + 128];
            float a11 = a12t[(k + 1) * 256 + c + 128];
            #pragma unroll
            for (int i = 0; i < 4; ++i) {
                float2 rv = *(const float2*)&rows[(rg * 4 + i) * 128 + k];
                accU[i] += a00 * rv.x + a01 * rv.y;
                accV[i] += a10 * rv.x + a11 * rv.y;
            }
        }
        #pragma unroll
        for (int i = 0; i < 4; ++i) {
            int r = r0 + rg * 4 + i;
            if (r < n) {
                U[(size_t)r * 128 + c] = accU[i];
                V[(size_t)r * 128 + c] = accV[i];
            }
        }
        __syncthreads();
    }
}

// su[n] = dot(U[n], a_2), sv[n] = dot(V[n], a_2)  (one wave per node)
__global__ void k1b_suv(const float* __restrict__ U, const float* __restrict__ V,
                        const float* __restrict__ a2, float* __restrict__ su,
                        float* __restrict__ sv, int n) {
    int w = (int)(((size_t)blockIdx.x * blockDim.x + threadIdx.x) >> 6);
    int lane = threadIdx.x & 63;
    if (w >= n) return;
    float2 a2v = ((const float2*)a2)[lane];
    float2 u = ((const float2*)U)[(size_t)w * 64 + lane];
    float2 v = ((const float2*)V)[(size_t)w * 64 + lane];
    float pu = u.x * a2v.x + u.y * a2v.y;
    float pv = v.x * a2v.x + v.y * a2v.y;
    #pragma unroll
    for (int off = 32; off > 0; off >>= 1) {
        pu += __shfl_xor(pu, off);
        pv += __shfl_xor(pv, off);
    }
    if (lane == 0) { su[w] = pu; sv[w] = pv; }
}

__global__ void k2_count(const int* __restrict__ edge, const int* __restrict__ flag,
                         int* __restrict__ counts, int E) {
    bool is64 = (*flag != 0);
    for (int i = blockIdx.x * blockDim.x + threadIdx.x; i < E; i += gridDim.x * blockDim.x) {
        int s = is64 ? edge[2 * (size_t)i] : edge[i];
        atomicAdd(&counts[s], 1);
    }
}

// single-block exclusive scan (wave-shuffle based)
__global__ __launch_bounds__(1024) void k3_scan(const int* __restrict__ counts,
                                                int* __restrict__ row_start,
                                                int* __restrict__ cursor, int n) {
    __shared__ int wsum[16];
    __shared__ int s_carry;
    int tid = threadIdx.x;
    int lane = tid & 63, wv = tid >> 6;
    if (tid == 0) s_carry = 0;
    __syncthreads();
    for (int base = 0; base < n; base += 1024) {
        int i = base + tid;
        int v = (i < n) ? counts[i] : 0;
        int x = v;
        #pragma unroll
        for (int off = 1; off < 64; off <<= 1) {
            int t = __shfl_up(x, off);
            if (lane >= off) x += t;
        }
        if (lane == 63) wsum[wv] = x;
        __syncthreads();
        int carry = s_carry;
        if (wv == 0) {
            int ws = (lane < 16) ? wsum[lane] : 0;
            #pragma unroll
            for (int off = 1; off < 16; off <<= 1) {
                int t = __shfl_up(ws, off);
                if (lane >= off) ws += t;
            }
            if (lane < 16) wsum[lane] = ws;
        }
        __syncthreads();
        int woff = (wv > 0) ? wsum[wv - 1] : 0;
        int excl = carry + woff + (x - v);
        if (i < n) { row_start[i] = excl; cursor[i] = excl; }
        if (tid == 0) s_carry = carry + wsum[15];
        __syncthreads();
    }
    if (tid == 0) row_start[n] = s_carry;
}

__global__ void k4_scatter(const int* __restrict__ edge, const int* __restrict__ flag,
                           int* __restrict__ cursor, int* __restrict__ eids,
                           int* __restrict__ dsts, int E) {
    bool is64 = (*flag != 0);
    for (int i = blockIdx.x * blockDim.x + threadIdx.x; i < E; i += gridDim.x * blockDim.x) {
        int s, d;
        if (is64) { s = edge[2 * (size_t)i]; d = edge[2 * ((size_t)E + i)]; }
        else      { s = edge[i];             d = edge[(size_t)E + i]; }
        int pos = atomicAdd(&cursor[s], 1);
        eids[pos] = i;
        dsts[pos] = d;
    }
}

// one wave per node: walk CSR list, read edge_embed once, accumulate T/W/rowsum in regs
__global__ __launch_bounds__(256) void k5_agg(const float* __restrict__ edge_embed,
                                              const float* __restrict__ V,
                                              const float* __restrict__ su,
                                              const float* __restrict__ sv,
                                              const float* __restrict__ w3,
                                              const int* __restrict__ row_start,
                                              const int* __restrict__ eids,
                                              const int* __restrict__ dsts,
                                              float* __restrict__ T, float* __restrict__ W,
                                              float* __restrict__ rowsum, int n) {
    int w = (int)(((size_t)blockIdx.x * blockDim.x + threadIdx.x) >> 6);
    int lane = threadIdx.x & 63;
    if (w >= n) return;
    int start = row_start[w], end = row_start[w + 1];
    float2 w3v = ((const float2*)w3)[lane];
    float su_n = su[w];
    const float2* EE = (const float2*)edge_embed;
    const float2* VV = (const float2*)V;
    float2 Tacc = make_float2(0.f, 0.f), Wacc = make_float2(0.f, 0.f);
    float rs = 0.f;
    if (start < end) {
        int eid0 = eids[start], dst0 = dsts[start];
        float2 emb0 = EE[(size_t)eid0 * 64 + lane];
        float2 vv0  = VV[(size_t)dst0 * 64 + lane];
        float sv0 = sv[dst0];
        for (int e = start; e < end; ++e) {
            float2 emb1 = make_float2(0.f, 0.f), vv1 = make_float2(0.f, 0.f);
            float sv1 = 0.f;
            if (e + 1 < end) {  // software prefetch of next edge
                int eid1 = eids[e + 1], dst1 = dsts[e + 1];
                emb1 = EE[(size_t)eid1 * 64 + lane];
                vv1  = VV[(size_t)dst1 * 64 + lane];
                sv1 = sv[dst1];
            }
            float part = emb0.x * w3v.x + emb0.y * w3v.y;
            #pragma unroll
            for (int off = 32; off > 0; off >>= 1) part += __shfl_xor(part, off);
            float s = su_n + sv0 + part;
            float lr = (s > 0.f) ? s : 0.2f * s;
            float ee = expf(-lr);
            rs += ee;
            Tacc.x += ee * emb0.x; Tacc.y += ee * emb0.y;
            Wacc.x += ee * vv0.x;  Wacc.y += ee * vv0.y;
            emb0 = emb1; vv0 = vv1; sv0 = sv1;
        }
    }
    ((float2*)T)[(size_t)w * 64 + lane] = Tacc;
    ((float2*)W)[(size_t)w * 64 + lane] = Wacc;
    if (lane == 0) rowsum[w] = rs;
}

// out = elu(U + (T @ a3^T + W) / rowsum); rowsum==0 -> 0
__global__ __launch_bounds__(256) void k6_final(const float* __restrict__ a,
                                                const float* __restrict__ U,
                                                const float* __restrict__ T,
                                                const float* __restrict__ W,
                                                const float* __restrict__ rowsum,
                                                float* __restrict__ out, int n) {
    __shared__ float a3s[128 * 130];  // [c][k], pad 130 to dodge bank conflicts
    __shared__ float Ts[2 * 128];
    for (int idx = threadIdx.x; idx < 128 * 128; idx += 256) {
        int cc = idx >> 7, k = idx & 127;
        a3s[cc * 130 + k] = a[cc * 384 + 256 + k];
    }
    __syncthreads();
    int rr = threadIdx.x >> 7, c = threadIdx.x & 127;
    for (int pair = blockIdx.x; pair * 2 < n; pair += gridDim.x) {
        int r = pair * 2 + rr;
        Ts[rr * 128 + c] = (r < n) ? T[(size_t)r * 128 + c] : 0.f;
        __syncthreads();
        if (r < n) {
            float acc = 0.f;
            #pragma unroll 8
            for (int k = 0; k < 128; k += 2) {
                float2 av = *(const float2*)&a3s[c * 130 + k];
                float2 tv = *(const float2*)&Ts[rr * 128 + k];
                acc += av.x * tv.x + av.y * tv.y;
            }
            float rs = rowsum[r];
            float h = 0.f;
            if (rs > 0.f)
                h = U[(size_t)r * 128 + c] + (acc + W[(size_t)r * 128 + c]) / rs;
            out[(size_t)r * 128 + c] = (h > 0.f) ? h : expm1f(h);
        }
        __syncthreads();
    }
}

}  // namespace

extern "C" void kernel_launch(void* const* d_in, const int* in_sizes, int n_in,
                              void* d_out, int out_size, void* d_ws, size_t ws_size,
                              hipStream_t stream) {
    const float* input      = (const float*)d_in[0];
    const float* edge_embed = (const float*)d_in[1];
    const float* a          = (const float*)d_in[2];
    const float* a2         = (const float*)d_in[3];
    const int*   edge       = (const int*)d_in[4];
    float* out = (float*)d_out;

    const int n = in_sizes[0] / 128;   // 50000
    const int E = in_sizes[1] / 128;   // 1000000

    char* p = (char*)d_ws;
    auto carve = [&](size_t bytes) -> char* {
        char* q = p;
        p += (bytes + 255) & ~(size_t)255;
        return q;
    };
    float* U         = (float*)carve((size_t)n * 128 * 4);
    float* V         = (float*)carve((size_t)n * 128 * 4);
    float* T         = (float*)carve((size_t)n * 128 * 4);
    float* W         = (float*)carve((size_t)n * 128 * 4);
    float* su        = (float*)carve((size_t)n * 4);
    float* sv        = (float*)carve((size_t)n * 4);
    float* rowsum    = (float*)carve((size_t)n * 4);
    float* w3        = (float*)carve(128 * 4);
    int*   counts    = (int*)carve((size_t)n * 4);
    int*   row_start = (int*)carve((size_t)(n + 1) * 4);
    int*   cursor    = (int*)carve((size_t)n * 4);
    int*   eids      = (int*)carve((size_t)E * 4);
    int*   dsts      = (int*)carve((size_t)E * 4);
    int*   flag      = (int*)carve(4);

    hipMemsetAsync(counts, 0, (size_t)n * 4, stream);

    kdet<<<1, 64, 0, stream>>>(edge, flag);
    k0_w3<<<1, 128, 0, stream>>>(a, a2, w3);
    k1_uv<<<512, 256, 0, stream>>>(input, a, U, V, n);
    k1b_suv<<<(n + 3) / 4, 256, 0, stream>>>(U, V, a2, su, sv, n);
    k2_count<<<1024, 256, 0, stream>>>(edge, flag, counts, E);
    k3_scan<<<1, 1024, 0, stream>>>(counts, row_start, cursor, n);
    k4_scatter<<<1024, 256, 0, stream>>>(edge, flag, cursor, eids, dsts, E);
    k5_agg<<<(n + 3) / 4, 256, 0, stream>>>(edge_embed, V, su, sv, w3,
                                            row_start, eids, dsts, T, W, rowsum, n);
    k6_final<<<1024, 256, 0, stream>>>(a, U, T, W, rowsum, out, n);
}

// Round 2
// 520.759 us; speedup vs baseline: 1.3848x; 1.3848x over previous
//
#include <hip/hip_runtime.h>
#include <math.h>

namespace {

typedef __attribute__((ext_vector_type(8))) short short8;
typedef __attribute__((ext_vector_type(4))) float f32x4;

__device__ inline unsigned short f2bf(float x) {
    unsigned u = __float_as_uint(x);
    unsigned r = (u + 0x7FFF + ((u >> 16) & 1)) >> 16;
    return (unsigned short)r;
}

// detect whether `edge` is stored as int64 (high words of first 64 values all zero)
__global__ void kdet(const int* __restrict__ edge, int* __restrict__ flag) {
    int lane = threadIdx.x;
    int hw = edge[2 * lane + 1];
    unsigned long long b = __ballot(hw == 0);
    if (lane == 0) *flag = (b == ~0ull) ? 1 : 0;
}

// w3[k] = sum_j a_2[j] * a[j*384 + 256 + k]
__global__ void k0_w3(const float* __restrict__ a, const float* __restrict__ a2,
                      float* __restrict__ w3) {
    int k = threadIdx.x;
    float s = 0.f;
    for (int j = 0; j < 128; ++j) s += a2[j] * a[j * 384 + 256 + k];
    w3[k] = s;
}

// Pack weights into MFMA B-fragment order (bf16).
// Bp12: [16 nfrag][4 kstep][64 lane][8 j]  for [a1|a2] (N=256, K=128)
// Bp3 : [ 8 nfrag][4 kstep][64 lane][8 j]  for a3      (N=128, K=128)
__global__ void kp_pack(const float* __restrict__ a, unsigned short* __restrict__ Bp12,
                        unsigned short* __restrict__ Bp3) {
    int tid = blockIdx.x * blockDim.x + threadIdx.x;
    if (tid < 32768) {
        int j = tid & 7, l = (tid >> 3) & 63, s = (tid >> 9) & 3, f = tid >> 11;
        int col = f * 16 + (l & 15);
        int k = s * 32 + ((l >> 4) << 3) + j;
        float v = (col < 128) ? a[col * 384 + k] : a[(col - 128) * 384 + 128 + k];
        Bp12[tid] = f2bf(v);
    }
    if (tid < 16384) {
        int j = tid & 7, l = (tid >> 3) & 63, s = (tid >> 9) & 3, f = tid >> 11;
        int col = f * 16 + (l & 15);
        int k = s * 32 + ((l >> 4) << 3) + j;
        Bp3[tid] = f2bf(a[col * 384 + 256 + k]);
    }
}

// [U|V] = input @ [a1|a2]^T via bf16 MFMA. Block: 64 rows, 4 waves x 16 rows x 256 cols.
__global__ __launch_bounds__(256) void k1_mfma(const float* __restrict__ input,
                                               const unsigned short* __restrict__ Bp,
                                               float* __restrict__ U, float* __restrict__ V,
                                               int n) {
    __shared__ char Asb[16384];  // 64 rows x 128 bf16, XOR-swizzled
    int tid = threadIdx.x;
    int wid = tid >> 6, lane = tid & 63;
    int rb = blockIdx.x * 64;
    const float4* inp4 = (const float4*)input;
    for (int it = tid; it < 2048; it += 256) {
        int row = it >> 5, c4 = it & 31;
        int gr = rb + row;
        float4 v = make_float4(0.f, 0.f, 0.f, 0.f);
        if (gr < n) v = inp4[(size_t)gr * 32 + c4];
        unsigned long long pk = (unsigned long long)f2bf(v.x) |
                                ((unsigned long long)f2bf(v.y) << 16) |
                                ((unsigned long long)f2bf(v.z) << 32) |
                                ((unsigned long long)f2bf(v.w) << 48);
        int byte = (row * 256 + c4 * 8) ^ ((row & 7) << 4);
        *(unsigned long long*)(Asb + byte) = pk;
    }
    __syncthreads();

    f32x4 acc[16];
    #pragma unroll
    for (int f = 0; f < 16; ++f) acc[f] = (f32x4){0.f, 0.f, 0.f, 0.f};
    const short8* Bf = (const short8*)Bp;
    int arow = (wid << 4) | (lane & 15);
    int abase = arow * 256 + ((lane >> 4) << 4);
    int xorv = (arow & 7) << 4;
    #pragma unroll
    for (int s = 0; s < 4; ++s) {
        short8 af = *(const short8*)(Asb + ((abase + s * 64) ^ xorv));
        #pragma unroll
        for (int f = 0; f < 16; ++f)
            acc[f] = __builtin_amdgcn_mfma_f32_16x16x32_bf16(af, Bf[(f * 4 + s) * 64 + lane],
                                                             acc[f], 0, 0, 0);
    }

    int rloc = (wid << 4) + ((lane >> 4) << 2);
    int cbase = lane & 15;
    #pragma unroll
    for (int f = 0; f < 16; ++f) {
        int col = f * 16 + cbase;
        #pragma unroll
        for (int reg = 0; reg < 4; ++reg) {
            int r = rb + rloc + reg;
            if (r < n) {
                if (col < 128) U[(size_t)r * 128 + col] = acc[f][reg];
                else           V[(size_t)r * 128 + (col - 128)] = acc[f][reg];
            }
        }
    }
}

// su[n] = dot(U[n], a_2), sv[n] = dot(V[n], a_2)  (one wave per node)
__global__ void k1b_suv(const float* __restrict__ U, const float* __restrict__ V,
                        const float* __restrict__ a2, float* __restrict__ su,
                        float* __restrict__ sv, int n) {
    int w = (int)(((size_t)blockIdx.x * blockDim.x + threadIdx.x) >> 6);
    int lane = threadIdx.x & 63;
    if (w >= n) return;
    float2 a2v = ((const float2*)a2)[lane];
    float2 u = ((const float2*)U)[(size_t)w * 64 + lane];
    float2 v = ((const float2*)V)[(size_t)w * 64 + lane];
    float pu = u.x * a2v.x + u.y * a2v.y;
    float pv = v.x * a2v.x + v.y * a2v.y;
    #pragma unroll
    for (int off = 32; off > 0; off >>= 1) {
        pu += __shfl_xor(pu, off);
        pv += __shfl_xor(pv, off);
    }
    if (lane == 0) { su[w] = pu; sv[w] = pv; }
}

__global__ void k2_count(const int* __restrict__ edge, const int* __restrict__ flag,
                         int* __restrict__ counts, int E) {
    bool is64 = (*flag != 0);
    for (int i = blockIdx.x * blockDim.x + threadIdx.x; i < E; i += gridDim.x * blockDim.x) {
        int s = is64 ? edge[2 * (size_t)i] : edge[i];
        atomicAdd(&counts[s], 1);
    }
}

// single-block exclusive scan (wave-shuffle based)
__global__ __launch_bounds__(1024) void k3_scan(const int* __restrict__ counts,
                                                int* __restrict__ row_start,
                                                int* __restrict__ cursor, int n) {
    __shared__ int wsum[16];
    __shared__ int s_carry;
    int tid = threadIdx.x;
    int lane = tid & 63, wv = tid >> 6;
    if (tid == 0) s_carry = 0;
    __syncthreads();
    for (int base = 0; base < n; base += 1024) {
        int i = base + tid;
        int v = (i < n) ? counts[i] : 0;
        int x = v;
        #pragma unroll
        for (int off = 1; off < 64; off <<= 1) {
            int t = __shfl_up(x, off);
            if (lane >= off) x += t;
        }
        if (lane == 63) wsum[wv] = x;
        __syncthreads();
        int carry = s_carry;
        if (wv == 0) {
            int ws = (lane < 16) ? wsum[lane] : 0;
            #pragma unroll
            for (int off = 1; off < 16; off <<= 1) {
                int t = __shfl_up(ws, off);
                if (lane >= off) ws += t;
            }
            if (lane < 16) wsum[lane] = ws;
        }
        __syncthreads();
        int woff = (wv > 0) ? wsum[wv - 1] : 0;
        int excl = carry + woff + (x - v);
        if (i < n) { row_start[i] = excl; cursor[i] = excl; }
        if (tid == 0) s_carry = carry + wsum[15];
        __syncthreads();
    }
    if (tid == 0) row_start[n] = s_carry;
}

__global__ void k4_scatter(const int* __restrict__ edge, const int* __restrict__ flag,
                           int* __restrict__ cursor, int2* __restrict__ epack, int E) {
    bool is64 = (*flag != 0);
    for (int i = blockIdx.x * blockDim.x + threadIdx.x; i < E; i += gridDim.x * blockDim.x) {
        int s, d;
        if (is64) { s = edge[2 * (size_t)i]; d = edge[2 * ((size_t)E + i)]; }
        else      { s = edge[i];             d = edge[(size_t)E + i]; }
        int pos = atomicAdd(&cursor[s], 1);
        epack[pos] = make_int2(i, d);
    }
}

// one wave per node: walk CSR list, read edge_embed once, accumulate T/W/rowsum in regs
__global__ __launch_bounds__(256) void k5_agg(const float* __restrict__ edge_embed,
                                              const float* __restrict__ V,
                                              const float* __restrict__ su,
                                              const float* __restrict__ sv,
                                              const float* __restrict__ w3,
                                              const int* __restrict__ row_start,
                                              const int2* __restrict__ epack,
                                              float* __restrict__ T, float* __restrict__ W,
                                              float* __restrict__ rowsum, int n) {
    int w = (int)(((size_t)blockIdx.x * blockDim.x + threadIdx.x) >> 6);
    int lane = threadIdx.x & 63;
    if (w >= n) return;
    int start = row_start[w], end = row_start[w + 1];
    float2 w3v = ((const float2*)w3)[lane];
    float su_n = su[w];
    const float2* EE = (const float2*)edge_embed;
    const float2* VV = (const float2*)V;
    float2 Tacc = make_float2(0.f, 0.f), Wacc = make_float2(0.f, 0.f);
    float rs = 0.f;
    if (start < end) {
        int2 ed0 = epack[start];
        float2 emb0 = EE[(size_t)ed0.x * 64 + lane];
        float2 vv0  = VV[(size_t)ed0.y * 64 + lane];
        float sv0 = sv[ed0.y];
        for (int e = start; e < end; ++e) {
            float2 emb1 = make_float2(0.f, 0.f), vv1 = make_float2(0.f, 0.f);
            float sv1 = 0.f;
            if (e + 1 < end) {  // software prefetch of next edge
                int2 ed1 = epack[e + 1];
                emb1 = EE[(size_t)ed1.x * 64 + lane];
                vv1  = VV[(size_t)ed1.y * 64 + lane];
                sv1 = sv[ed1.y];
            }
            float part = emb0.x * w3v.x + emb0.y * w3v.y;
            #pragma unroll
            for (int off = 32; off > 0; off >>= 1) part += __shfl_xor(part, off);
            float s = su_n + sv0 + part;
            float lr = (s > 0.f) ? s : 0.2f * s;
            float ee = expf(-lr);
            rs += ee;
            Tacc.x += ee * emb0.x; Tacc.y += ee * emb0.y;
            Wacc.x += ee * vv0.x;  Wacc.y += ee * vv0.y;
            emb0 = emb1; vv0 = vv1; sv0 = sv1;
        }
    }
    ((float2*)T)[(size_t)w * 64 + lane] = Tacc;
    ((float2*)W)[(size_t)w * 64 + lane] = Wacc;
    if (lane == 0) rowsum[w] = rs;
}

// out = elu(U + (T @ a3^T + W) / rowsum) via bf16 MFMA; rowsum==0 -> 0
__global__ __launch_bounds__(256) void k6_mfma(const float* __restrict__ T,
                                               const unsigned short* __restrict__ Bp3,
                                               const float* __restrict__ U,
                                               const float* __restrict__ W,
                                               const float* __restrict__ rowsum,
                                               float* __restrict__ out, int n) {
    __shared__ char Asb[16384];
    int tid = threadIdx.x;
    int wid = tid >> 6, lane = tid & 63;
    int rb = blockIdx.x * 64;
    const float4* t4 = (const float4*)T;
    for (int it = tid; it < 2048; it += 256) {
        int row = it >> 5, c4 = it & 31;
        int gr = rb + row;
        float4 v = make_float4(0.f, 0.f, 0.f, 0.f);
        if (gr < n) v = t4[(size_t)gr * 32 + c4];
        unsigned long long pk = (unsigned long long)f2bf(v.x) |
                                ((unsigned long long)f2bf(v.y) << 16) |
                                ((unsigned long long)f2bf(v.z) << 32) |
                                ((unsigned long long)f2bf(v.w) << 48);
        int byte = (row * 256 + c4 * 8) ^ ((row & 7) << 4);
        *(unsigned long long*)(Asb + byte) = pk;
    }
    __syncthreads();

    f32x4 acc[8];
    #pragma unroll
    for (int f = 0; f < 8; ++f) acc[f] = (f32x4){0.f, 0.f, 0.f, 0.f};
    const short8* Bf = (const short8*)Bp3;
    int arow = (wid << 4) | (lane & 15);
    int abase = arow * 256 + ((lane >> 4) << 4);
    int xorv = (arow & 7) << 4;
    #pragma unroll
    for (int s = 0; s < 4; ++s) {
        short8 af = *(const short8*)(Asb + ((abase + s * 64) ^ xorv));
        #pragma unroll
        for (int f = 0; f < 8; ++f)
            acc[f] = __builtin_amdgcn_mfma_f32_16x16x32_bf16(af, Bf[(f * 4 + s) * 64 + lane],
                                                             acc[f], 0, 0, 0);
    }

    int rloc = (wid << 4) + ((lane >> 4) << 2);
    int cbase = lane & 15;
    #pragma unroll
    for (int f = 0; f < 8; ++f) {
        int col = f * 16 + cbase;
        #pragma unroll
        for (int reg = 0; reg < 4; ++reg) {
            int r = rb + rloc + reg;
            if (r < n) {
                float rs = rowsum[r];
                float h = 0.f;
                if (rs > 0.f)
                    h = U[(size_t)r * 128 + col] + (acc[f][reg] + W[(size_t)r * 128 + col]) / rs;
                out[(size_t)r * 128 + col] = (h > 0.f) ? h : expm1f(h);
            }
        }
    }
}

}  // namespace

extern "C" void kernel_launch(void* const* d_in, const int* in_sizes, int n_in,
                              void* d_out, int out_size, void* d_ws, size_t ws_size,
                              hipStream_t stream) {
    const float* input      = (const float*)d_in[0];
    const float* edge_embed = (const float*)d_in[1];
    const float* a          = (const float*)d_in[2];
    const float* a2         = (const float*)d_in[3];
    const int*   edge       = (const int*)d_in[4];
    float* out = (float*)d_out;

    const int n = in_sizes[0] / 128;   // 50000
    const int E = in_sizes[1] / 128;   // 1000000

    char* p = (char*)d_ws;
    auto carve = [&](size_t bytes) -> char* {
        char* q = p;
        p += (bytes + 255) & ~(size_t)255;
        return q;
    };
    float* U         = (float*)carve((size_t)n * 128 * 4);
    float* V         = (float*)carve((size_t)n * 128 * 4);
    float* T         = (float*)carve((size_t)n * 128 * 4);
    float* W         = (float*)carve((size_t)n * 128 * 4);
    float* su        = (float*)carve((size_t)n * 4);
    float* sv        = (float*)carve((size_t)n * 4);
    float* rowsum    = (float*)carve((size_t)n * 4);
    float* w3        = (float*)carve(128 * 4);
    int*   counts    = (int*)carve((size_t)n * 4);
    int*   row_start = (int*)carve((size_t)(n + 1) * 4);
    int*   cursor    = (int*)carve((size_t)n * 4);
    int2*  epack     = (int2*)carve((size_t)E * 8);
    unsigned short* Bp12 = (unsigned short*)carve(32768 * 2);
    unsigned short* Bp3  = (unsigned short*)carve(16384 * 2);
    int*   flag      = (int*)carve(4);

    hipMemsetAsync(counts, 0, (size_t)n * 4, stream);

    kdet<<<1, 64, 0, stream>>>(edge, flag);
    kp_pack<<<128, 256, 0, stream>>>(a, Bp12, Bp3);
    k0_w3<<<1, 128, 0, stream>>>(a, a2, w3);
    k1_mfma<<<(n + 63) / 64, 256, 0, stream>>>(input, Bp12, U, V, n);
    k1b_suv<<<(n + 3) / 4, 256, 0, stream>>>(U, V, a2, su, sv, n);
    k2_count<<<1024, 256, 0, stream>>>(edge, flag, counts, E);
    k3_scan<<<1, 1024, 0, stream>>>(counts, row_start, cursor, n);
    k4_scatter<<<1024, 256, 0, stream>>>(edge, flag, cursor, epack, E);
    k5_agg<<<(n + 3) / 4, 256, 0, stream>>>(edge_embed, V, su, sv, w3,
                                            row_start, epack, T, W, rowsum, n);
    k6_mfma<<<(n + 63) / 64, 256, 0, stream>>>(T, Bp3, U, W, rowsum, out, n);
}

// Round 3
// 462.491 us; speedup vs baseline: 1.5593x; 1.1260x over previous
//
#include <hip/hip_runtime.h>
#include <math.h>

namespace {

typedef __attribute__((ext_vector_type(8))) short short8;
typedef __attribute__((ext_vector_type(4))) float f32x4;

__device__ inline unsigned short f2bf(float x) {
    unsigned u = __float_as_uint(x);
    unsigned r = (u + 0x7FFF + ((u >> 16) & 1)) >> 16;
    return (unsigned short)r;
}

// detect whether `edge` is stored as int64 (high words of first 64 values all zero)
__global__ void kdet(const int* __restrict__ edge, int* __restrict__ flag) {
    int lane = threadIdx.x;
    int hw = edge[2 * lane + 1];
    unsigned long long b = __ballot(hw == 0);
    if (lane == 0) *flag = (b == ~0ull) ? 1 : 0;
}

// w3[k] = sum_j a_2[j] * a[j*384 + 256 + k]
__global__ void k0_w3(const float* __restrict__ a, const float* __restrict__ a2,
                      float* __restrict__ w3) {
    int k = threadIdx.x;
    float s = 0.f;
    for (int j = 0; j < 128; ++j) s += a2[j] * a[j * 384 + 256 + k];
    w3[k] = s;
}

// Pack weights into MFMA B-fragment order (bf16).
__global__ void kp_pack(const float* __restrict__ a, unsigned short* __restrict__ Bp12,
                        unsigned short* __restrict__ Bp3) {
    int tid = blockIdx.x * blockDim.x + threadIdx.x;
    if (tid < 32768) {
        int j = tid & 7, l = (tid >> 3) & 63, s = (tid >> 9) & 3, f = tid >> 11;
        int col = f * 16 + (l & 15);
        int k = s * 32 + ((l >> 4) << 3) + j;
        float v = (col < 128) ? a[col * 384 + k] : a[(col - 128) * 384 + 128 + k];
        Bp12[tid] = f2bf(v);
    }
    if (tid < 16384) {
        int j = tid & 7, l = (tid >> 3) & 63, s = (tid >> 9) & 3, f = tid >> 11;
        int col = f * 16 + (l & 15);
        int k = s * 32 + ((l >> 4) << 3) + j;
        Bp3[tid] = f2bf(a[col * 384 + 256 + k]);
    }
}

// [U|V] = input @ [a1|a2]^T via bf16 MFMA; su/sv fused in epilogue.
__global__ __launch_bounds__(256) void k1_mfma(const float* __restrict__ input,
                                               const unsigned short* __restrict__ Bp,
                                               const float* __restrict__ a2,
                                               float* __restrict__ U, float* __restrict__ V,
                                               float* __restrict__ su, float* __restrict__ sv,
                                               int n) {
    __shared__ char Asb[16384];  // 64 rows x 128 bf16, XOR-swizzled
    int tid = threadIdx.x;
    int wid = tid >> 6, lane = tid & 63;
    int rb = blockIdx.x * 64;
    const float4* inp4 = (const float4*)input;
    for (int it = tid; it < 2048; it += 256) {
        int row = it >> 5, c4 = it & 31;
        int gr = rb + row;
        float4 v = make_float4(0.f, 0.f, 0.f, 0.f);
        if (gr < n) v = inp4[(size_t)gr * 32 + c4];
        unsigned long long pk = (unsigned long long)f2bf(v.x) |
                                ((unsigned long long)f2bf(v.y) << 16) |
                                ((unsigned long long)f2bf(v.z) << 32) |
                                ((unsigned long long)f2bf(v.w) << 48);
        int byte = (row * 256 + c4 * 8) ^ ((row & 7) << 4);
        *(unsigned long long*)(Asb + byte) = pk;
    }
    __syncthreads();

    f32x4 acc[16];
    #pragma unroll
    for (int f = 0; f < 16; ++f) acc[f] = (f32x4){0.f, 0.f, 0.f, 0.f};
    const short8* Bf = (const short8*)Bp;
    int arow = (wid << 4) | (lane & 15);
    int abase = arow * 256 + ((lane >> 4) << 4);
    int xorv = (arow & 7) << 4;
    #pragma unroll
    for (int s = 0; s < 4; ++s) {
        short8 af = *(const short8*)(Asb + ((abase + s * 64) ^ xorv));
        #pragma unroll
        for (int f = 0; f < 16; ++f)
            acc[f] = __builtin_amdgcn_mfma_f32_16x16x32_bf16(af, Bf[(f * 4 + s) * 64 + lane],
                                                             acc[f], 0, 0, 0);
    }

    int rloc = (wid << 4) + ((lane >> 4) << 2);
    int cb = lane & 15;
    #pragma unroll
    for (int f = 0; f < 16; ++f) {
        int col = f * 16 + cb;
        #pragma unroll
        for (int reg = 0; reg < 4; ++reg) {
            int r = rb + rloc + reg;
            if (r < n) {
                if (col < 128) U[(size_t)r * 128 + col] = acc[f][reg];
                else           V[(size_t)r * 128 + (col - 128)] = acc[f][reg];
            }
        }
    }

    // fused su/sv: dot each output row with a_2, reduced across the 16-lane col group
    float coefU[8], coefV[8];
    #pragma unroll
    for (int f = 0; f < 8; ++f) {
        coefU[f] = a2[f * 16 + cb];
        coefV[f] = a2[f * 16 + cb];  // V cols use same a2 index (col-128)
    }
    #pragma unroll
    for (int reg = 0; reg < 4; ++reg) {
        float pu = 0.f, pv = 0.f;
        #pragma unroll
        for (int f = 0; f < 8; ++f) {
            pu += acc[f][reg] * coefU[f];
            pv += acc[f + 8][reg] * coefV[f];
        }
        #pragma unroll
        for (int off = 1; off < 16; off <<= 1) {
            pu += __shfl_xor(pu, off);
            pv += __shfl_xor(pv, off);
        }
        int r = rb + rloc + reg;
        if (cb == 0 && r < n) { su[r] = pu; sv[r] = pv; }
    }
}

__global__ void k2_count(const int* __restrict__ edge, const int* __restrict__ flag,
                         int* __restrict__ counts, int E) {
    bool is64 = (*flag != 0);
    int half = E >> 1;
    int stride = gridDim.x * blockDim.x;
    for (int i = blockIdx.x * blockDim.x + threadIdx.x; i < half; i += stride) {
        int s0, s1;
        if (is64) { int4 v = ((const int4*)edge)[i]; s0 = v.x; s1 = v.z; }
        else      { int2 v = ((const int2*)edge)[i]; s0 = v.x; s1 = v.y; }
        atomicAdd(&counts[s0], 1);
        atomicAdd(&counts[s1], 1);
    }
    if ((E & 1) && blockIdx.x == 0 && threadIdx.x == 0) {
        int i = E - 1;
        int s = is64 ? edge[2 * (size_t)i] : edge[i];
        atomicAdd(&counts[s], 1);
    }
}

// hierarchical scan: k3a local scan (chunk=1024), k3b scan partials, k3c add offsets
__global__ __launch_bounds__(1024) void k3a(const int* __restrict__ counts,
                                            int* __restrict__ row_start,
                                            int* __restrict__ partials, int n) {
    __shared__ int wsum[16];
    int tid = threadIdx.x;
    int i = blockIdx.x * 1024 + tid;
    int lane = tid & 63, wv = tid >> 6;
    int v = (i < n) ? counts[i] : 0;
    int x = v;
    #pragma unroll
    for (int off = 1; off < 64; off <<= 1) {
        int t = __shfl_up(x, off);
        if (lane >= off) x += t;
    }
    if (lane == 63) wsum[wv] = x;
    __syncthreads();
    if (wv == 0) {
        int ws = (lane < 16) ? wsum[lane] : 0;
        #pragma unroll
        for (int off = 1; off < 16; off <<= 1) {
            int t = __shfl_up(ws, off);
            if (lane >= off) ws += t;
        }
        if (lane < 16) wsum[lane] = ws;
    }
    __syncthreads();
    int woff = (wv > 0) ? wsum[wv - 1] : 0;
    if (i < n) row_start[i] = woff + x - v;
    if (tid == 1023) partials[blockIdx.x] = wsum[15];
}

__global__ void k3b(const int* __restrict__ partials, int* __restrict__ poffs,
                    int* __restrict__ row_start, int nb, int n) {
    int lane = threadIdx.x;  // 64 threads
    int carry = 0;
    for (int base = 0; base < nb; base += 64) {
        int v = (base + lane < nb) ? partials[base + lane] : 0;
        int x = v;
        #pragma unroll
        for (int off = 1; off < 64; off <<= 1) {
            int t = __shfl_up(x, off);
            if (lane >= off) x += t;
        }
        if (base + lane < nb) poffs[base + lane] = carry + x - v;
        carry += __shfl(x, 63);
    }
    if (lane == 0) row_start[n] = carry;
}

__global__ __launch_bounds__(1024) void k3c(const int* __restrict__ poffs,
                                            int* __restrict__ row_start,
                                            int* __restrict__ cursor, int n) {
    int i = blockIdx.x * 1024 + threadIdx.x;
    if (i < n) {
        int v = row_start[i] + poffs[blockIdx.x];
        row_start[i] = v;
        cursor[i] = v;
    }
}

__global__ void k4_scatter(const int* __restrict__ edge, const int* __restrict__ flag,
                           int* __restrict__ cursor, int2* __restrict__ epack, int E) {
    bool is64 = (*flag != 0);
    int half = E >> 1;
    int stride = gridDim.x * blockDim.x;
    const int* dbase = edge + (is64 ? 2 * (size_t)E : (size_t)E);
    for (int i = blockIdx.x * blockDim.x + threadIdx.x; i < half; i += stride) {
        int s0, s1, d0, d1;
        if (is64) {
            int4 v = ((const int4*)edge)[i];  s0 = v.x; s1 = v.z;
            int4 w = ((const int4*)dbase)[i]; d0 = w.x; d1 = w.z;
        } else {
            int2 v = ((const int2*)edge)[i];  s0 = v.x; s1 = v.y;
            int2 w = ((const int2*)dbase)[i]; d0 = w.x; d1 = w.y;
        }
        int p0 = atomicAdd(&cursor[s0], 1);
        epack[p0] = make_int2(2 * i, d0);
        int p1 = atomicAdd(&cursor[s1], 1);
        epack[p1] = make_int2(2 * i + 1, d1);
    }
    if ((E & 1) && blockIdx.x == 0 && threadIdx.x == 0) {
        int i = E - 1;
        int s = is64 ? edge[2 * (size_t)i] : edge[i];
        int d = is64 ? dbase[2 * (size_t)i] : dbase[i];
        int pos = atomicAdd(&cursor[s], 1);
        epack[pos] = make_int2(i, d);
    }
}

// one wave per node; 8-edge batches for ILP on gathers and pipelined butterfly reduce
__global__ __launch_bounds__(256) void k5_agg(const float* __restrict__ edge_embed,
                                              const float* __restrict__ V,
                                              const float* __restrict__ su,
                                              const float* __restrict__ sv,
                                              const float* __restrict__ w3,
                                              const int* __restrict__ row_start,
                                              const int2* __restrict__ epack,
                                              float* __restrict__ T, float* __restrict__ W,
                                              float* __restrict__ rowsum, int n) {
    int w = (int)(((size_t)blockIdx.x * blockDim.x + threadIdx.x) >> 6);
    int lane = threadIdx.x & 63;
    if (w >= n) return;
    int start = row_start[w], end = row_start[w + 1];
    float2 w3v = ((const float2*)w3)[lane];
    float su_n = su[w];
    const float2* EE = (const float2*)edge_embed;
    const float2* VV = (const float2*)V;
    float2 Tacc = make_float2(0.f, 0.f), Wacc = make_float2(0.f, 0.f);
    float rs = 0.f;
    for (int e0 = start; e0 < end; e0 += 8) {
        int nb = end - e0;
        if (nb > 8) nb = 8;
        float2 emb[8], vv[8];
        float svv[8], part[8];
        #pragma unroll
        for (int i = 0; i < 8; ++i) {
            if (i < nb) {
                int2 ed = epack[e0 + i];
                emb[i] = EE[(size_t)ed.x * 64 + lane];
                vv[i]  = VV[(size_t)ed.y * 64 + lane];
                svv[i] = sv[ed.y];
            } else {
                emb[i] = make_float2(0.f, 0.f);
                vv[i]  = make_float2(0.f, 0.f);
                svv[i] = 0.f;
            }
        }
        #pragma unroll
        for (int i = 0; i < 8; ++i)
            part[i] = emb[i].x * w3v.x + emb[i].y * w3v.y;
        #pragma unroll
        for (int off = 32; off > 0; off >>= 1) {
            #pragma unroll
            for (int i = 0; i < 8; ++i)
                part[i] += __shfl_xor(part[i], off);
        }
        #pragma unroll
        for (int i = 0; i < 8; ++i) {
            if (i < nb) {
                float s = su_n + svv[i] + part[i];
                float lr = (s > 0.f) ? s : 0.2f * s;
                float ee = __expf(-lr);
                rs += ee;
                Tacc.x += ee * emb[i].x; Tacc.y += ee * emb[i].y;
                Wacc.x += ee * vv[i].x;  Wacc.y += ee * vv[i].y;
            }
        }
    }
    ((float2*)T)[(size_t)w * 64 + lane] = Tacc;
    ((float2*)W)[(size_t)w * 64 + lane] = Wacc;
    if (lane == 0) rowsum[w] = rs;
}

// out = elu(U + (T @ a3^T + W) / rowsum) via bf16 MFMA; rowsum==0 -> 0
__global__ __launch_bounds__(256) void k6_mfma(const float* __restrict__ T,
                                               const unsigned short* __restrict__ Bp3,
                                               const float* __restrict__ U,
                                               const float* __restrict__ W,
                                               const float* __restrict__ rowsum,
                                               float* __restrict__ out, int n) {
    __shared__ char Asb[16384];
    int tid = threadIdx.x;
    int wid = tid >> 6, lane = tid & 63;
    int rb = blockIdx.x * 64;
    const float4* t4 = (const float4*)T;
    for (int it = tid; it < 2048; it += 256) {
        int row = it >> 5, c4 = it & 31;
        int gr = rb + row;
        float4 v = make_float4(0.f, 0.f, 0.f, 0.f);
        if (gr < n) v = t4[(size_t)gr * 32 + c4];
        unsigned long long pk = (unsigned long long)f2bf(v.x) |
                                ((unsigned long long)f2bf(v.y) << 16) |
                                ((unsigned long long)f2bf(v.z) << 32) |
                                ((unsigned long long)f2bf(v.w) << 48);
        int byte = (row * 256 + c4 * 8) ^ ((row & 7) << 4);
        *(unsigned long long*)(Asb + byte) = pk;
    }
    __syncthreads();

    f32x4 acc[8];
    #pragma unroll
    for (int f = 0; f < 8; ++f) acc[f] = (f32x4){0.f, 0.f, 0.f, 0.f};
    const short8* Bf = (const short8*)Bp3;
    int arow = (wid << 4) | (lane & 15);
    int abase = arow * 256 + ((lane >> 4) << 4);
    int xorv = (arow & 7) << 4;
    #pragma unroll
    for (int s = 0; s < 4; ++s) {
        short8 af = *(const short8*)(Asb + ((abase + s * 64) ^ xorv));
        #pragma unroll
        for (int f = 0; f < 8; ++f)
            acc[f] = __builtin_amdgcn_mfma_f32_16x16x32_bf16(af, Bf[(f * 4 + s) * 64 + lane],
                                                             acc[f], 0, 0, 0);
    }

    int rloc = (wid << 4) + ((lane >> 4) << 2);
    int cbase = lane & 15;
    #pragma unroll
    for (int f = 0; f < 8; ++f) {
        int col = f * 16 + cbase;
        #pragma unroll
        for (int reg = 0; reg < 4; ++reg) {
            int r = rb + rloc + reg;
            if (r < n) {
                float rs = rowsum[r];
                float h = 0.f;
                if (rs > 0.f)
                    h = U[(size_t)r * 128 + col] + (acc[f][reg] + W[(size_t)r * 128 + col]) / rs;
                out[(size_t)r * 128 + col] = (h > 0.f) ? h : expm1f(h);
            }
        }
    }
}

}  // namespace

extern "C" void kernel_launch(void* const* d_in, const int* in_sizes, int n_in,
                              void* d_out, int out_size, void* d_ws, size_t ws_size,
                              hipStream_t stream) {
    const float* input      = (const float*)d_in[0];
    const float* edge_embed = (const float*)d_in[1];
    const float* a          = (const float*)d_in[2];
    const float* a2         = (const float*)d_in[3];
    const int*   edge       = (const int*)d_in[4];
    float* out = (float*)d_out;

    const int n = in_sizes[0] / 128;   // 50000
    const int E = in_sizes[1] / 128;   // 1000000

    char* p = (char*)d_ws;
    auto carve = [&](size_t bytes) -> char* {
        char* q = p;
        p += (bytes + 255) & ~(size_t)255;
        return q;
    };
    float* U         = (float*)carve((size_t)n * 128 * 4);
    float* V         = (float*)carve((size_t)n * 128 * 4);
    float* T         = (float*)carve((size_t)n * 128 * 4);
    float* W         = (float*)carve((size_t)n * 128 * 4);
    float* su        = (float*)carve((size_t)n * 4);
    float* sv        = (float*)carve((size_t)n * 4);
    float* rowsum    = (float*)carve((size_t)n * 4);
    float* w3        = (float*)carve(128 * 4);
    int*   counts    = (int*)carve((size_t)n * 4);
    int*   row_start = (int*)carve((size_t)(n + 1) * 4);
    int*   cursor    = (int*)carve((size_t)n * 4);
    int2*  epack     = (int2*)carve((size_t)E * 8);
    unsigned short* Bp12 = (unsigned short*)carve(32768 * 2);
    unsigned short* Bp3  = (unsigned short*)carve(16384 * 2);
    int*   partials  = (int*)carve(4096 * 4);
    int*   poffs     = (int*)carve(4096 * 4);
    int*   flag      = (int*)carve(4);

    const int NB = (n + 1023) / 1024;

    hipMemsetAsync(counts, 0, (size_t)n * 4, stream);

    kdet<<<1, 64, 0, stream>>>(edge, flag);
    kp_pack<<<128, 256, 0, stream>>>(a, Bp12, Bp3);
    k0_w3<<<1, 128, 0, stream>>>(a, a2, w3);
    k1_mfma<<<(n + 63) / 64, 256, 0, stream>>>(input, Bp12, a2, U, V, su, sv, n);
    k2_count<<<1024, 256, 0, stream>>>(edge, flag, counts, E);
    k3a<<<NB, 1024, 0, stream>>>(counts, row_start, partials, n);
    k3b<<<1, 64, 0, stream>>>(partials, poffs, row_start, NB, n);
    k3c<<<NB, 1024, 0, stream>>>(poffs, row_start, cursor, n);
    k4_scatter<<<1024, 256, 0, stream>>>(edge, flag, cursor, epack, E);
    k5_agg<<<(n + 3) / 4, 256, 0, stream>>>(edge_embed, V, su, sv, w3,
                                            row_start, epack, T, W, rowsum, n);
    k6_mfma<<<(n + 63) / 64, 256, 0, stream>>>(T, Bp3, U, W, rowsum, out, n);
}

// Round 4
// 428.136 us; speedup vs baseline: 1.6844x; 1.0802x over previous
//
#include <hip/hip_runtime.h>
#include <math.h>

namespace {

typedef __attribute__((ext_vector_type(8))) short short8;
typedef __attribute__((ext_vector_type(4))) float f32x4;
typedef __attribute__((ext_vector_type(2))) float f2v;

__device__ inline unsigned short f2bf(float x) {
    unsigned u = __float_as_uint(x);
    unsigned r = (u + 0x7FFF + ((u >> 16) & 1)) >> 16;
    return (unsigned short)r;
}

__device__ inline f2v nt2(const f2v* p) { return __builtin_nontemporal_load(p); }
__device__ inline long long ntll(const long long* p) { return __builtin_nontemporal_load(p); }

// fused prologue: edge-dtype detect + w3 + weight pack (grid 128 x 256)
__global__ void kprep(const int* __restrict__ edge, const float* __restrict__ a,
                      const float* __restrict__ a2, int* __restrict__ flag,
                      unsigned short* __restrict__ Bp12, unsigned short* __restrict__ Bp3,
                      float* __restrict__ w3) {
    int tid = blockIdx.x * blockDim.x + threadIdx.x;
    if (tid < 32768) {
        int j = tid & 7, l = (tid >> 3) & 63, s = (tid >> 9) & 3, f = tid >> 11;
        int col = f * 16 + (l & 15);
        int k = s * 32 + ((l >> 4) << 3) + j;
        float v = (col < 128) ? a[col * 384 + k] : a[(col - 128) * 384 + 128 + k];
        Bp12[tid] = f2bf(v);
    }
    if (tid < 16384) {
        int j = tid & 7, l = (tid >> 3) & 63, s = (tid >> 9) & 3, f = tid >> 11;
        int col = f * 16 + (l & 15);
        int k = s * 32 + ((l >> 4) << 3) + j;
        Bp3[tid] = f2bf(a[col * 384 + 256 + k]);
    }
    if (blockIdx.x == 0 && threadIdx.x < 64) {
        int hw = edge[2 * threadIdx.x + 1];
        unsigned long long b = __ballot(hw == 0);
        if (threadIdx.x == 0) *flag = (b == ~0ull) ? 1 : 0;
    }
    if (blockIdx.x == 1 && threadIdx.x < 128) {
        int k = threadIdx.x;
        float s = 0.f;
        for (int j = 0; j < 128; ++j) s += a2[j] * a[j * 384 + 256 + k];
        w3[k] = s;
    }
}

// [U|V] = input @ [a1|a2]^T via bf16 MFMA; su/sv fused in epilogue.
__global__ __launch_bounds__(256) void k1_mfma(const float* __restrict__ input,
                                               const unsigned short* __restrict__ Bp,
                                               const float* __restrict__ a2,
                                               float* __restrict__ U, float* __restrict__ V,
                                               float* __restrict__ su, float* __restrict__ sv,
                                               int n) {
    __shared__ char Asb[16384];  // 64 rows x 128 bf16, XOR-swizzled
    int tid = threadIdx.x;
    int wid = tid >> 6, lane = tid & 63;
    int rb = blockIdx.x * 64;
    const float4* inp4 = (const float4*)input;
    for (int it = tid; it < 2048; it += 256) {
        int row = it >> 5, c4 = it & 31;
        int gr = rb + row;
        float4 v = make_float4(0.f, 0.f, 0.f, 0.f);
        if (gr < n) v = inp4[(size_t)gr * 32 + c4];
        unsigned long long pk = (unsigned long long)f2bf(v.x) |
                                ((unsigned long long)f2bf(v.y) << 16) |
                                ((unsigned long long)f2bf(v.z) << 32) |
                                ((unsigned long long)f2bf(v.w) << 48);
        int byte = (row * 256 + c4 * 8) ^ ((row & 7) << 4);
        *(unsigned long long*)(Asb + byte) = pk;
    }
    __syncthreads();

    f32x4 acc[16];
    #pragma unroll
    for (int f = 0; f < 16; ++f) acc[f] = (f32x4){0.f, 0.f, 0.f, 0.f};
    const short8* Bf = (const short8*)Bp;
    int arow = (wid << 4) | (lane & 15);
    int abase = arow * 256 + ((lane >> 4) << 4);
    int xorv = (arow & 7) << 4;
    #pragma unroll
    for (int s = 0; s < 4; ++s) {
        short8 af = *(const short8*)(Asb + ((abase + s * 64) ^ xorv));
        #pragma unroll
        for (int f = 0; f < 16; ++f)
            acc[f] = __builtin_amdgcn_mfma_f32_16x16x32_bf16(af, Bf[(f * 4 + s) * 64 + lane],
                                                             acc[f], 0, 0, 0);
    }

    int rloc = (wid << 4) + ((lane >> 4) << 2);
    int cb = lane & 15;
    #pragma unroll
    for (int f = 0; f < 16; ++f) {
        int col = f * 16 + cb;
        #pragma unroll
        for (int reg = 0; reg < 4; ++reg) {
            int r = rb + rloc + reg;
            if (r < n) {
                if (col < 128) U[(size_t)r * 128 + col] = acc[f][reg];
                else           V[(size_t)r * 128 + (col - 128)] = acc[f][reg];
            }
        }
    }

    float coef[8];
    #pragma unroll
    for (int f = 0; f < 8; ++f) coef[f] = a2[f * 16 + cb];
    #pragma unroll
    for (int reg = 0; reg < 4; ++reg) {
        float pu = 0.f, pv = 0.f;
        #pragma unroll
        for (int f = 0; f < 8; ++f) {
            pu += acc[f][reg] * coef[f];
            pv += acc[f + 8][reg] * coef[f];
        }
        #pragma unroll
        for (int off = 1; off < 16; off <<= 1) {
            pu += __shfl_xor(pu, off);
            pv += __shfl_xor(pv, off);
        }
        int r = rb + rloc + reg;
        if (cb == 0 && r < n) { su[r] = pu; sv[r] = pv; }
    }
}

__global__ void k2_count(const int* __restrict__ edge, const int* __restrict__ flag,
                         int* __restrict__ counts, int E) {
    bool is64 = (*flag != 0);
    int half = E >> 1;
    int stride = gridDim.x * blockDim.x;
    for (int i = blockIdx.x * blockDim.x + threadIdx.x; i < half; i += stride) {
        int s0, s1;
        if (is64) { int4 v = ((const int4*)edge)[i]; s0 = v.x; s1 = v.z; }
        else      { int2 v = ((const int2*)edge)[i]; s0 = v.x; s1 = v.y; }
        atomicAdd(&counts[s0], 1);
        atomicAdd(&counts[s1], 1);
    }
    if ((E & 1) && blockIdx.x == 0 && threadIdx.x == 0) {
        int i = E - 1;
        int s = is64 ? edge[2 * (size_t)i] : edge[i];
        atomicAdd(&counts[s], 1);
    }
}

// hierarchical scan
__global__ __launch_bounds__(1024) void k3a(const int* __restrict__ counts,
                                            int* __restrict__ row_start,
                                            int* __restrict__ partials, int n) {
    __shared__ int wsum[16];
    int tid = threadIdx.x;
    int i = blockIdx.x * 1024 + tid;
    int lane = tid & 63, wv = tid >> 6;
    int v = (i < n) ? counts[i] : 0;
    int x = v;
    #pragma unroll
    for (int off = 1; off < 64; off <<= 1) {
        int t = __shfl_up(x, off);
        if (lane >= off) x += t;
    }
    if (lane == 63) wsum[wv] = x;
    __syncthreads();
    if (wv == 0) {
        int ws = (lane < 16) ? wsum[lane] : 0;
        #pragma unroll
        for (int off = 1; off < 16; off <<= 1) {
            int t = __shfl_up(ws, off);
            if (lane >= off) ws += t;
        }
        if (lane < 16) wsum[lane] = ws;
    }
    __syncthreads();
    int woff = (wv > 0) ? wsum[wv - 1] : 0;
    if (i < n) row_start[i] = woff + x - v;
    if (tid == 1023) partials[blockIdx.x] = wsum[15];
}

__global__ void k3b(const int* __restrict__ partials, int* __restrict__ poffs,
                    int* __restrict__ row_start, int nb, int n) {
    int lane = threadIdx.x;  // 64 threads
    int carry = 0;
    for (int base = 0; base < nb; base += 64) {
        int v = (base + lane < nb) ? partials[base + lane] : 0;
        int x = v;
        #pragma unroll
        for (int off = 1; off < 64; off <<= 1) {
            int t = __shfl_up(x, off);
            if (lane >= off) x += t;
        }
        if (base + lane < nb) poffs[base + lane] = carry + x - v;
        carry += __shfl(x, 63);
    }
    if (lane == 0) row_start[n] = carry;
}

__global__ __launch_bounds__(1024) void k3c(const int* __restrict__ poffs,
                                            int* __restrict__ row_start,
                                            int* __restrict__ cursor, int n) {
    int i = blockIdx.x * 1024 + threadIdx.x;
    if (i < n) {
        int v = row_start[i] + poffs[blockIdx.x];
        row_start[i] = v;
        cursor[i] = v;
    }
}

__global__ void k4_scatter(const int* __restrict__ edge, const int* __restrict__ flag,
                           int* __restrict__ cursor, long long* __restrict__ epack, int E) {
    bool is64 = (*flag != 0);
    int half = E >> 1;
    int stride = gridDim.x * blockDim.x;
    const int* dbase = edge + (is64 ? 2 * (size_t)E : (size_t)E);
    for (int i = blockIdx.x * blockDim.x + threadIdx.x; i < half; i += stride) {
        int s0, s1, d0, d1;
        if (is64) {
            int4 v = ((const int4*)edge)[i];  s0 = v.x; s1 = v.z;
            int4 w = ((const int4*)dbase)[i]; d0 = w.x; d1 = w.z;
        } else {
            int2 v = ((const int2*)edge)[i];  s0 = v.x; s1 = v.y;
            int2 w = ((const int2*)dbase)[i]; d0 = w.x; d1 = w.y;
        }
        int p0 = atomicAdd(&cursor[s0], 1);
        long long pk0 = (long long)(unsigned)(2 * i) | ((long long)(unsigned)d0 << 32);
        __builtin_nontemporal_store(pk0, &epack[p0]);
        int p1 = atomicAdd(&cursor[s1], 1);
        long long pk1 = (long long)(unsigned)(2 * i + 1) | ((long long)(unsigned)d1 << 32);
        __builtin_nontemporal_store(pk1, &epack[p1]);
    }
    if ((E & 1) && blockIdx.x == 0 && threadIdx.x == 0) {
        int i = E - 1;
        int s = is64 ? edge[2 * (size_t)i] : edge[i];
        int d = is64 ? dbase[2 * (size_t)i] : dbase[i];
        int pos = atomicAdd(&cursor[s], 1);
        long long pk = (long long)(unsigned)i | ((long long)(unsigned)d << 32);
        __builtin_nontemporal_store(pk, &epack[pos]);
    }
}

// one wave per node; 8-edge batches, nt streaming loads, cross-batch epack prefetch
__global__ __launch_bounds__(256, 4) void k5_agg(const float* __restrict__ edge_embed,
                                                 const float* __restrict__ V,
                                                 const float* __restrict__ su,
                                                 const float* __restrict__ sv,
                                                 const float* __restrict__ w3,
                                                 const int* __restrict__ row_start,
                                                 const long long* __restrict__ epack,
                                                 float* __restrict__ T, float* __restrict__ W,
                                                 float* __restrict__ rowsum, int n) {
    int w = (int)(((size_t)blockIdx.x * blockDim.x + threadIdx.x) >> 6);
    int lane = threadIdx.x & 63;
    if (w >= n) return;
    int start = row_start[w], end = row_start[w + 1];
    f2v w3v = ((const f2v*)w3)[lane];
    float su_n = su[w];
    const f2v* EE = (const f2v*)edge_embed;
    const f2v* VV = (const f2v*)V;
    f2v Tacc = 0.f, Wacc = 0.f;
    float rs = 0.f;
    long long eds[8];
    #pragma unroll
    for (int i = 0; i < 8; ++i)
        eds[i] = (start + i < end) ? ntll(&epack[start + i]) : 0;
    for (int e0 = start; e0 < end; e0 += 8) {
        int nb = end - e0;
        if (nb > 8) nb = 8;
        long long edsn[8];
        #pragma unroll
        for (int i = 0; i < 8; ++i) {
            int idx = e0 + 8 + i;
            edsn[i] = (idx < end) ? ntll(&epack[idx]) : 0;
        }
        f2v emb[8], vv[8];
        float svv[8], part[8];
        #pragma unroll
        for (int i = 0; i < 8; ++i) {
            if (i < nb) {
                int eid = (int)eds[i];
                int dst = (int)(eds[i] >> 32);
                emb[i] = nt2(EE + (size_t)eid * 64 + lane);
                vv[i]  = VV[(size_t)dst * 64 + lane];
                svv[i] = sv[dst];
            } else {
                emb[i] = 0.f; vv[i] = 0.f; svv[i] = 0.f;
            }
        }
        #pragma unroll
        for (int i = 0; i < 8; ++i)
            part[i] = emb[i].x * w3v.x + emb[i].y * w3v.y;
        #pragma unroll
        for (int off = 32; off > 0; off >>= 1) {
            #pragma unroll
            for (int i = 0; i < 8; ++i)
                part[i] += __shfl_xor(part[i], off);
        }
        #pragma unroll
        for (int i = 0; i < 8; ++i) {
            if (i < nb) {
                float s = su_n + svv[i] + part[i];
                float lr = (s > 0.f) ? s : 0.2f * s;
                float ee = __expf(-lr);
                rs += ee;
                Tacc += ee * emb[i];
                Wacc += ee * vv[i];
            }
        }
        #pragma unroll
        for (int i = 0; i < 8; ++i) eds[i] = edsn[i];
    }
    __builtin_nontemporal_store(Tacc, (f2v*)T + (size_t)w * 64 + lane);
    __builtin_nontemporal_store(Wacc, (f2v*)W + (size_t)w * 64 + lane);
    if (lane == 0) __builtin_nontemporal_store(rs, &rowsum[w]);
}

// out = elu(U + (T @ a3^T + W) / rowsum) via bf16 MFMA; rowsum==0 -> 0
__global__ __launch_bounds__(256) void k6_mfma(const float* __restrict__ T,
                                               const unsigned short* __restrict__ Bp3,
                                               const float* __restrict__ U,
                                               const float* __restrict__ W,
                                               const float* __restrict__ rowsum,
                                               float* __restrict__ out, int n) {
    __shared__ char Asb[16384];
    int tid = threadIdx.x;
    int wid = tid >> 6, lane = tid & 63;
    int rb = blockIdx.x * 64;
    const f32x4* t4 = (const f32x4*)T;
    for (int it = tid; it < 2048; it += 256) {
        int row = it >> 5, c4 = it & 31;
        int gr = rb + row;
        f32x4 v = 0.f;
        if (gr < n) v = __builtin_nontemporal_load(t4 + (size_t)gr * 32 + c4);
        unsigned long long pk = (unsigned long long)f2bf(v.x) |
                                ((unsigned long long)f2bf(v.y) << 16) |
                                ((unsigned long long)f2bf(v.z) << 32) |
                                ((unsigned long long)f2bf(v.w) << 48);
        int byte = (row * 256 + c4 * 8) ^ ((row & 7) << 4);
        *(unsigned long long*)(Asb + byte) = pk;
    }
    __syncthreads();

    f32x4 acc[8];
    #pragma unroll
    for (int f = 0; f < 8; ++f) acc[f] = (f32x4){0.f, 0.f, 0.f, 0.f};
    const short8* Bf = (const short8*)Bp3;
    int arow = (wid << 4) | (lane & 15);
    int abase = arow * 256 + ((lane >> 4) << 4);
    int xorv = (arow & 7) << 4;
    #pragma unroll
    for (int s = 0; s < 4; ++s) {
        short8 af = *(const short8*)(Asb + ((abase + s * 64) ^ xorv));
        #pragma unroll
        for (int f = 0; f < 8; ++f)
            acc[f] = __builtin_amdgcn_mfma_f32_16x16x32_bf16(af, Bf[(f * 4 + s) * 64 + lane],
                                                             acc[f], 0, 0, 0);
    }

    int rloc = (wid << 4) + ((lane >> 4) << 2);
    int cbase = lane & 15;
    #pragma unroll
    for (int f = 0; f < 8; ++f) {
        int col = f * 16 + cbase;
        #pragma unroll
        for (int reg = 0; reg < 4; ++reg) {
            int r = rb + rloc + reg;
            if (r < n) {
                float rs = rowsum[r];
                float h = 0.f;
                if (rs > 0.f) {
                    float u = __builtin_nontemporal_load(&U[(size_t)r * 128 + col]);
                    float ww = __builtin_nontemporal_load(&W[(size_t)r * 128 + col]);
                    h = u + (acc[f][reg] + ww) / rs;
                }
                float o = (h > 0.f) ? h : expm1f(h);
                __builtin_nontemporal_store(o, &out[(size_t)r * 128 + col]);
            }
        }
    }
}

}  // namespace

extern "C" void kernel_launch(void* const* d_in, const int* in_sizes, int n_in,
                              void* d_out, int out_size, void* d_ws, size_t ws_size,
                              hipStream_t stream) {
    const float* input      = (const float*)d_in[0];
    const float* edge_embed = (const float*)d_in[1];
    const float* a          = (const float*)d_in[2];
    const float* a2         = (const float*)d_in[3];
    const int*   edge       = (const int*)d_in[4];
    float* out = (float*)d_out;

    const int n = in_sizes[0] / 128;   // 50000
    const int E = in_sizes[1] / 128;   // 1000000

    char* p = (char*)d_ws;
    auto carve = [&](size_t bytes) -> char* {
        char* q = p;
        p += (bytes + 255) & ~(size_t)255;
        return q;
    };
    float* U         = (float*)carve((size_t)n * 128 * 4);
    float* V         = (float*)carve((size_t)n * 128 * 4);
    float* T         = (float*)carve((size_t)n * 128 * 4);
    float* W         = (float*)carve((size_t)n * 128 * 4);
    float* su        = (float*)carve((size_t)n * 4);
    float* sv        = (float*)carve((size_t)n * 4);
    float* rowsum    = (float*)carve((size_t)n * 4);
    float* w3        = (float*)carve(128 * 4);
    int*   counts    = (int*)carve((size_t)n * 4);
    int*   row_start = (int*)carve((size_t)(n + 1) * 4);
    int*   cursor    = (int*)carve((size_t)n * 4);
    long long* epack = (long long*)carve((size_t)E * 8);
    unsigned short* Bp12 = (unsigned short*)carve(32768 * 2);
    unsigned short* Bp3  = (unsigned short*)carve(16384 * 2);
    int*   partials  = (int*)carve(4096 * 4);
    int*   poffs     = (int*)carve(4096 * 4);
    int*   flag      = (int*)carve(4);

    const int NB = (n + 1023) / 1024;

    hipMemsetAsync(counts, 0, (size_t)n * 4, stream);

    kprep<<<128, 256, 0, stream>>>(edge, a, a2, flag, Bp12, Bp3, w3);
    k1_mfma<<<(n + 63) / 64, 256, 0, stream>>>(input, Bp12, a2, U, V, su, sv, n);
    k2_count<<<1024, 256, 0, stream>>>(edge, flag, counts, E);
    k3a<<<NB, 1024, 0, stream>>>(counts, row_start, partials, n);
    k3b<<<1, 64, 0, stream>>>(partials, poffs, row_start, NB, n);
    k3c<<<NB, 1024, 0, stream>>>(poffs, row_start, cursor, n);
    k4_scatter<<<1024, 256, 0, stream>>>(edge, flag, cursor, epack, E);
    k5_agg<<<(n + 3) / 4, 256, 0, stream>>>(edge_embed, V, su, sv, w3,
                                            row_start, epack, T, W, rowsum, n);
    k6_mfma<<<(n + 63) / 64, 256, 0, stream>>>(T, Bp3, U, W, rowsum, out, n);
}

// Round 5
// 401.106 us; speedup vs baseline: 1.7979x; 1.0674x over previous
//
#include <hip/hip_runtime.h>
#include <math.h>

namespace {

typedef __attribute__((ext_vector_type(8))) short short8;
typedef __attribute__((ext_vector_type(4))) float f32x4;
typedef __attribute__((ext_vector_type(2))) float f2v;

__device__ inline unsigned short f2bf(float x) {
    unsigned u = __float_as_uint(x);
    unsigned r = (u + 0x7FFF + ((u >> 16) & 1)) >> 16;
    return (unsigned short)r;
}

__device__ inline f2v nt2(const f2v* p) { return __builtin_nontemporal_load(p); }
__device__ inline long long ntll(const long long* p) { return __builtin_nontemporal_load(p); }

// full-wave (64-lane) sum via DPP on the VALU pipe — no LDS-pipe traffic.
// row_shr 1/2/4/8 within 16-lane rows, then row_bcast:15 (rows 1,3) and
// row_bcast:31 (rows 2,3); lane 63 holds the total; readlane broadcasts.
__device__ inline float wave_sum64(float x) {
    int t;
    t = __builtin_amdgcn_update_dpp(0, __float_as_int(x), 0x111, 0xf, 0xf, true);
    x += __int_as_float(t);
    t = __builtin_amdgcn_update_dpp(0, __float_as_int(x), 0x112, 0xf, 0xf, true);
    x += __int_as_float(t);
    t = __builtin_amdgcn_update_dpp(0, __float_as_int(x), 0x114, 0xf, 0xf, true);
    x += __int_as_float(t);
    t = __builtin_amdgcn_update_dpp(0, __float_as_int(x), 0x118, 0xf, 0xf, true);
    x += __int_as_float(t);
    t = __builtin_amdgcn_update_dpp(0, __float_as_int(x), 0x142, 0xa, 0xf, true);
    x += __int_as_float(t);
    t = __builtin_amdgcn_update_dpp(0, __float_as_int(x), 0x143, 0xc, 0xf, true);
    x += __int_as_float(t);
    return __int_as_float(__builtin_amdgcn_readlane(__float_as_int(x), 63));
}

// fused prologue: edge-dtype detect + w3 + weight pack (grid 128 x 256)
__global__ void kprep(const int* __restrict__ edge, const float* __restrict__ a,
                      const float* __restrict__ a2, int* __restrict__ flag,
                      unsigned short* __restrict__ Bp12, unsigned short* __restrict__ Bp3,
                      float* __restrict__ w3) {
    int tid = blockIdx.x * blockDim.x + threadIdx.x;
    if (tid < 32768) {
        int j = tid & 7, l = (tid >> 3) & 63, s = (tid >> 9) & 3, f = tid >> 11;
        int col = f * 16 + (l & 15);
        int k = s * 32 + ((l >> 4) << 3) + j;
        float v = (col < 128) ? a[col * 384 + k] : a[(col - 128) * 384 + 128 + k];
        Bp12[tid] = f2bf(v);
    }
    if (tid < 16384) {
        int j = tid & 7, l = (tid >> 3) & 63, s = (tid >> 9) & 3, f = tid >> 11;
        int col = f * 16 + (l & 15);
        int k = s * 32 + ((l >> 4) << 3) + j;
        Bp3[tid] = f2bf(a[col * 384 + 256 + k]);
    }
    if (blockIdx.x == 0 && threadIdx.x < 64) {
        int hw = edge[2 * threadIdx.x + 1];
        unsigned long long b = __ballot(hw == 0);
        if (threadIdx.x == 0) *flag = (b == ~0ull) ? 1 : 0;
    }
    if (blockIdx.x == 1 && threadIdx.x < 128) {
        int k = threadIdx.x;
        float s = 0.f;
        for (int j = 0; j < 128; ++j) s += a2[j] * a[j * 384 + 256 + k];
        w3[k] = s;
    }
}

// Fused: blocks [0, nb1) do the U/V MFMA GEMM; blocks [nb1, nb1+1024) do edge counting.
__global__ __launch_bounds__(256) void kA(const float* __restrict__ input,
                                          const unsigned short* __restrict__ Bp,
                                          const float* __restrict__ a2,
                                          float* __restrict__ U, float* __restrict__ V,
                                          float* __restrict__ su, float* __restrict__ sv,
                                          const int* __restrict__ edge,
                                          const int* __restrict__ flag,
                                          int* __restrict__ counts,
                                          int n, int E, int nb1) {
    __shared__ char Asb[16384];  // 64 rows x 128 bf16, XOR-swizzled
    if (blockIdx.x >= nb1) {
        // ---- k2_count body ----
        bool is64 = (*flag != 0);
        int half = E >> 1;
        int stride = 1024 * 256;
        for (int i = (blockIdx.x - nb1) * 256 + threadIdx.x; i < half; i += stride) {
            int s0, s1;
            if (is64) { int4 v = ((const int4*)edge)[i]; s0 = v.x; s1 = v.z; }
            else      { int2 v = ((const int2*)edge)[i]; s0 = v.x; s1 = v.y; }
            atomicAdd(&counts[s0], 1);
            atomicAdd(&counts[s1], 1);
        }
        if ((E & 1) && blockIdx.x == nb1 && threadIdx.x == 0) {
            int i = E - 1;
            int s = is64 ? edge[2 * (size_t)i] : edge[i];
            atomicAdd(&counts[s], 1);
        }
        return;
    }
    // ---- k1_mfma body ----
    int tid = threadIdx.x;
    int wid = tid >> 6, lane = tid & 63;
    int rb = blockIdx.x * 64;
    const float4* inp4 = (const float4*)input;
    for (int it = tid; it < 2048; it += 256) {
        int row = it >> 5, c4 = it & 31;
        int gr = rb + row;
        float4 v = make_float4(0.f, 0.f, 0.f, 0.f);
        if (gr < n) v = inp4[(size_t)gr * 32 + c4];
        unsigned long long pk = (unsigned long long)f2bf(v.x) |
                                ((unsigned long long)f2bf(v.y) << 16) |
                                ((unsigned long long)f2bf(v.z) << 32) |
                                ((unsigned long long)f2bf(v.w) << 48);
        int byte = (row * 256 + c4 * 8) ^ ((row & 7) << 4);
        *(unsigned long long*)(Asb + byte) = pk;
    }
    __syncthreads();

    f32x4 acc[16];
    #pragma unroll
    for (int f = 0; f < 16; ++f) acc[f] = (f32x4){0.f, 0.f, 0.f, 0.f};
    const short8* Bf = (const short8*)Bp;
    int arow = (wid << 4) | (lane & 15);
    int abase = arow * 256 + ((lane >> 4) << 4);
    int xorv = (arow & 7) << 4;
    #pragma unroll
    for (int s = 0; s < 4; ++s) {
        short8 af = *(const short8*)(Asb + ((abase + s * 64) ^ xorv));
        #pragma unroll
        for (int f = 0; f < 16; ++f)
            acc[f] = __builtin_amdgcn_mfma_f32_16x16x32_bf16(af, Bf[(f * 4 + s) * 64 + lane],
                                                             acc[f], 0, 0, 0);
    }

    int rloc = (wid << 4) + ((lane >> 4) << 2);
    int cb = lane & 15;
    #pragma unroll
    for (int f = 0; f < 16; ++f) {
        int col = f * 16 + cb;
        #pragma unroll
        for (int reg = 0; reg < 4; ++reg) {
            int r = rb + rloc + reg;
            if (r < n) {
                if (col < 128) U[(size_t)r * 128 + col] = acc[f][reg];
                else           V[(size_t)r * 128 + (col - 128)] = acc[f][reg];
            }
        }
    }

    float coef[8];
    #pragma unroll
    for (int f = 0; f < 8; ++f) coef[f] = a2[f * 16 + cb];
    #pragma unroll
    for (int reg = 0; reg < 4; ++reg) {
        float pu = 0.f, pv = 0.f;
        #pragma unroll
        for (int f = 0; f < 8; ++f) {
            pu += acc[f][reg] * coef[f];
            pv += acc[f + 8][reg] * coef[f];
        }
        #pragma unroll
        for (int off = 1; off < 16; off <<= 1) {
            pu += __shfl_xor(pu, off);
            pv += __shfl_xor(pv, off);
        }
        int r = rb + rloc + reg;
        if (cb == 0 && r < n) { su[r] = pu; sv[r] = pv; }
    }
}

// hierarchical scan
__global__ __launch_bounds__(1024) void k3a(const int* __restrict__ counts,
                                            int* __restrict__ row_start,
                                            int* __restrict__ partials, int n) {
    __shared__ int wsum[16];
    int tid = threadIdx.x;
    int i = blockIdx.x * 1024 + tid;
    int lane = tid & 63, wv = tid >> 6;
    int v = (i < n) ? counts[i] : 0;
    int x = v;
    #pragma unroll
    for (int off = 1; off < 64; off <<= 1) {
        int t = __shfl_up(x, off);
        if (lane >= off) x += t;
    }
    if (lane == 63) wsum[wv] = x;
    __syncthreads();
    if (wv == 0) {
        int ws = (lane < 16) ? wsum[lane] : 0;
        #pragma unroll
        for (int off = 1; off < 16; off <<= 1) {
            int t = __shfl_up(ws, off);
            if (lane >= off) ws += t;
        }
        if (lane < 16) wsum[lane] = ws;
    }
    __syncthreads();
    int woff = (wv > 0) ? wsum[wv - 1] : 0;
    if (i < n) row_start[i] = woff + x - v;
    if (tid == 1023) partials[blockIdx.x] = wsum[15];
}

__global__ void k3b(const int* __restrict__ partials, int* __restrict__ poffs,
                    int* __restrict__ row_start, int nb, int n) {
    int lane = threadIdx.x;  // 64 threads
    int carry = 0;
    for (int base = 0; base < nb; base += 64) {
        int v = (base + lane < nb) ? partials[base + lane] : 0;
        int x = v;
        #pragma unroll
        for (int off = 1; off < 64; off <<= 1) {
            int t = __shfl_up(x, off);
            if (lane >= off) x += t;
        }
        if (base + lane < nb) poffs[base + lane] = carry + x - v;
        carry += __shfl(x, 63);
    }
    if (lane == 0) row_start[n] = carry;
}

__global__ __launch_bounds__(1024) void k3c(const int* __restrict__ poffs,
                                            int* __restrict__ row_start,
                                            int* __restrict__ cursor, int n) {
    int i = blockIdx.x * 1024 + threadIdx.x;
    if (i < n) {
        int v = row_start[i] + poffs[blockIdx.x];
        row_start[i] = v;
        cursor[i] = v;
    }
}

__global__ void k4_scatter(const int* __restrict__ edge, const int* __restrict__ flag,
                           int* __restrict__ cursor, long long* __restrict__ epack, int E) {
    bool is64 = (*flag != 0);
    int half = E >> 1;
    int stride = gridDim.x * blockDim.x;
    const int* dbase = edge + (is64 ? 2 * (size_t)E : (size_t)E);
    for (int i = blockIdx.x * blockDim.x + threadIdx.x; i < half; i += stride) {
        int s0, s1, d0, d1;
        if (is64) {
            int4 v = ((const int4*)edge)[i];  s0 = v.x; s1 = v.z;
            int4 w = ((const int4*)dbase)[i]; d0 = w.x; d1 = w.z;
        } else {
            int2 v = ((const int2*)edge)[i];  s0 = v.x; s1 = v.y;
            int2 w = ((const int2*)dbase)[i]; d0 = w.x; d1 = w.y;
        }
        int p0 = atomicAdd(&cursor[s0], 1);
        epack[p0] = (long long)(unsigned)(2 * i) | ((long long)(unsigned)d0 << 32);
        int p1 = atomicAdd(&cursor[s1], 1);
        epack[p1] = (long long)(unsigned)(2 * i + 1) | ((long long)(unsigned)d1 << 32);
    }
    if ((E & 1) && blockIdx.x == 0 && threadIdx.x == 0) {
        int i = E - 1;
        int s = is64 ? edge[2 * (size_t)i] : edge[i];
        int d = is64 ? dbase[2 * (size_t)i] : dbase[i];
        int pos = atomicAdd(&cursor[s], 1);
        epack[pos] = (long long)(unsigned)i | ((long long)(unsigned)d << 32);
    }
}

// one wave per node; 8-edge batches, nt streaming loads, DPP score reduction
__global__ __launch_bounds__(256, 4) void k5_agg(const float* __restrict__ edge_embed,
                                                 const float* __restrict__ V,
                                                 const float* __restrict__ su,
                                                 const float* __restrict__ sv,
                                                 const float* __restrict__ w3,
                                                 const int* __restrict__ row_start,
                                                 const long long* __restrict__ epack,
                                                 float* __restrict__ T, float* __restrict__ W,
                                                 float* __restrict__ rowsum, int n) {
    int w = (int)(((size_t)blockIdx.x * blockDim.x + threadIdx.x) >> 6);
    int lane = threadIdx.x & 63;
    if (w >= n) return;
    int start = row_start[w], end = row_start[w + 1];
    f2v w3v = ((const f2v*)w3)[lane];
    float su_n = su[w];
    const f2v* EE = (const f2v*)edge_embed;
    const f2v* VV = (const f2v*)V;
    f2v Tacc = 0.f, Wacc = 0.f;
    float rs = 0.f;
    long long eds[8];
    #pragma unroll
    for (int i = 0; i < 8; ++i)
        eds[i] = (start + i < end) ? ntll(&epack[start + i]) : 0;
    for (int e0 = start; e0 < end; e0 += 8) {
        int nb = end - e0;
        if (nb > 8) nb = 8;
        long long edsn[8];
        #pragma unroll
        for (int i = 0; i < 8; ++i) {
            int idx = e0 + 8 + i;
            edsn[i] = (idx < end) ? ntll(&epack[idx]) : 0;
        }
        f2v emb[8], vv[8];
        float svv[8], part[8];
        #pragma unroll
        for (int i = 0; i < 8; ++i) {
            if (i < nb) {
                int eid = (int)eds[i];
                int dst = (int)(eds[i] >> 32);
                emb[i] = nt2(EE + (size_t)eid * 64 + lane);
                vv[i]  = VV[(size_t)dst * 64 + lane];
                svv[i] = sv[dst];
            } else {
                emb[i] = 0.f; vv[i] = 0.f; svv[i] = 0.f;
            }
        }
        #pragma unroll
        for (int i = 0; i < 8; ++i)
            part[i] = wave_sum64(emb[i].x * w3v.x + emb[i].y * w3v.y);
        #pragma unroll
        for (int i = 0; i < 8; ++i) {
            if (i < nb) {
                float s = su_n + svv[i] + part[i];
                float lr = (s > 0.f) ? s : 0.2f * s;
                float ee = __expf(-lr);
                rs += ee;
                Tacc += ee * emb[i];
                Wacc += ee * vv[i];
            }
        }
        #pragma unroll
        for (int i = 0; i < 8; ++i) eds[i] = edsn[i];
    }
    __builtin_nontemporal_store(Tacc, (f2v*)T + (size_t)w * 64 + lane);
    __builtin_nontemporal_store(Wacc, (f2v*)W + (size_t)w * 64 + lane);
    if (lane == 0) __builtin_nontemporal_store(rs, &rowsum[w]);
}

// out = elu(U + (T @ a3^T + W) / rowsum) via bf16 MFMA; rowsum==0 -> 0
__global__ __launch_bounds__(256) void k6_mfma(const float* __restrict__ T,
                                               const unsigned short* __restrict__ Bp3,
                                               const float* __restrict__ U,
                                               const float* __restrict__ W,
                                               const float* __restrict__ rowsum,
                                               float* __restrict__ out, int n) {
    __shared__ char Asb[16384];
    int tid = threadIdx.x;
    int wid = tid >> 6, lane = tid & 63;
    int rb = blockIdx.x * 64;
    const f32x4* t4 = (const f32x4*)T;
    for (int it = tid; it < 2048; it += 256) {
        int row = it >> 5, c4 = it & 31;
        int gr = rb + row;
        f32x4 v = 0.f;
        if (gr < n) v = __builtin_nontemporal_load(t4 + (size_t)gr * 32 + c4);
        unsigned long long pk = (unsigned long long)f2bf(v.x) |
                                ((unsigned long long)f2bf(v.y) << 16) |
                                ((unsigned long long)f2bf(v.z) << 32) |
                                ((unsigned long long)f2bf(v.w) << 48);
        int byte = (row * 256 + c4 * 8) ^ ((row & 7) << 4);
        *(unsigned long long*)(Asb + byte) = pk;
    }
    __syncthreads();

    f32x4 acc[8];
    #pragma unroll
    for (int f = 0; f < 8; ++f) acc[f] = (f32x4){0.f, 0.f, 0.f, 0.f};
    const short8* Bf = (const short8*)Bp3;
    int arow = (wid << 4) | (lane & 15);
    int abase = arow * 256 + ((lane >> 4) << 4);
    int xorv = (arow & 7) << 4;
    #pragma unroll
    for (int s = 0; s < 4; ++s) {
        short8 af = *(const short8*)(Asb + ((abase + s * 64) ^ xorv));
        #pragma unroll
        for (int f = 0; f < 8; ++f)
            acc[f] = __builtin_amdgcn_mfma_f32_16x16x32_bf16(af, Bf[(f * 4 + s) * 64 + lane],
                                                             acc[f], 0, 0, 0);
    }

    int rloc = (wid << 4) + ((lane >> 4) << 2);
    int cbase = lane & 15;
    #pragma unroll
    for (int f = 0; f < 8; ++f) {
        int col = f * 16 + cbase;
        #pragma unroll
        for (int reg = 0; reg < 4; ++reg) {
            int r = rb + rloc + reg;
            if (r < n) {
                float rs = rowsum[r];
                float h = 0.f;
                if (rs > 0.f) {
                    float u = __builtin_nontemporal_load(&U[(size_t)r * 128 + col]);
                    float ww = __builtin_nontemporal_load(&W[(size_t)r * 128 + col]);
                    h = u + (acc[f][reg] + ww) / rs;
                }
                float o = (h > 0.f) ? h : expm1f(h);
                __builtin_nontemporal_store(o, &out[(size_t)r * 128 + col]);
            }
        }
    }
}

}  // namespace

extern "C" void kernel_launch(void* const* d_in, const int* in_sizes, int n_in,
                              void* d_out, int out_size, void* d_ws, size_t ws_size,
                              hipStream_t stream) {
    const float* input      = (const float*)d_in[0];
    const float* edge_embed = (const float*)d_in[1];
    const float* a          = (const float*)d_in[2];
    const float* a2         = (const float*)d_in[3];
    const int*   edge       = (const int*)d_in[4];
    float* out = (float*)d_out;

    const int n = in_sizes[0] / 128;   // 50000
    const int E = in_sizes[1] / 128;   // 1000000

    char* p = (char*)d_ws;
    auto carve = [&](size_t bytes) -> char* {
        char* q = p;
        p += (bytes + 255) & ~(size_t)255;
        return q;
    };
    float* U         = (float*)carve((size_t)n * 128 * 4);
    float* V         = (float*)carve((size_t)n * 128 * 4);
    float* T         = (float*)carve((size_t)n * 128 * 4);
    float* W         = (float*)carve((size_t)n * 128 * 4);
    float* su        = (float*)carve((size_t)n * 4);
    float* sv        = (float*)carve((size_t)n * 4);
    float* rowsum    = (float*)carve((size_t)n * 4);
    float* w3        = (float*)carve(128 * 4);
    int*   counts    = (int*)carve((size_t)n * 4);
    int*   row_start = (int*)carve((size_t)(n + 1) * 4);
    int*   cursor    = (int*)carve((size_t)n * 4);
    long long* epack = (long long*)carve((size_t)E * 8);
    unsigned short* Bp12 = (unsigned short*)carve(32768 * 2);
    unsigned short* Bp3  = (unsigned short*)carve(16384 * 2);
    int*   partials  = (int*)carve(4096 * 4);
    int*   poffs     = (int*)carve(4096 * 4);
    int*   flag      = (int*)carve(4);

    const int NB = (n + 1023) / 1024;
    const int nb1 = (n + 63) / 64;

    hipMemsetAsync(counts, 0, (size_t)n * 4, stream);

    kprep<<<128, 256, 0, stream>>>(edge, a, a2, flag, Bp12, Bp3, w3);
    kA<<<nb1 + 1024, 256, 0, stream>>>(input, Bp12, a2, U, V, su, sv,
                                       edge, flag, counts, n, E, nb1);
    k3a<<<NB, 1024, 0, stream>>>(counts, row_start, partials, n);
    k3b<<<1, 64, 0, stream>>>(partials, poffs, row_start, NB, n);
    k3c<<<NB, 1024, 0, stream>>>(poffs, row_start, cursor, n);
    k4_scatter<<<1024, 256, 0, stream>>>(edge, flag, cursor, epack, E);
    k5_agg<<<(n + 3) / 4, 256, 0, stream>>>(edge_embed, V, su, sv, w3,
                                            row_start, epack, T, W, rowsum, n);
    k6_mfma<<<(n + 63) / 64, 256, 0, stream>>>(T, Bp3, U, W, rowsum, out, n);
}